// Round 6
// baseline (60.569 us; speedup 1.0000x reference)
//
#include <hip/hip_runtime.h>
#include <hip/hip_bf16.h>
#include <math.h>

typedef __attribute__((ext_vector_type(8))) short short8;
typedef __attribute__((ext_vector_type(16))) float f32x16;

union U {
    unsigned u[4];
    short8 s;
};

struct FragH {         // one component (re or im) bf16 operand, 2 k-tiles
    U f[2];
};

static __device__ __forceinline__ unsigned short f2bf(float x) {
    __bf16 b = (__bf16)x;                       // RNE, native v_cvt on gfx950
    return __builtin_bit_cast(unsigned short, b);
}
static __device__ __forceinline__ unsigned packbf(float a, float b) {
    return (unsigned)f2bf(a) | ((unsigned)f2bf(b) << 16);
}

#define MFMA(A, B, C) __builtin_amdgcn_mfma_f32_32x32x16_bf16((A).s, (B).s, (C), 0, 0, 0)

// ---------------------------------------------------------------------------
// Workspace layout (bytes):
//   0      : tabs  float2[4096]  (F, Finv, -, conj-twiddle -- for kf_kernel)
//   32768  : T1    float2[1024]  (pure twiddle exp(-2pi i rc/N), C/D order; NO 1/N)
//   49152  : Ftab  uint4 [384]   (bf16 fragment tables: re, im, +sin)
//   65536  : kf_cd float2[128*1024] (filter spectrum / 1024, C/D order)
// ---------------------------------------------------------------------------

__global__ __launch_bounds__(256) void fft_tables(float2* tabs, float2* T1, uint4* Ftab) {
    int gid = blockIdx.x * 256 + threadIdx.x;       // grid 16*256 = 4096
    if (gid < 1024) {
        int i = gid;
        int r = i >> 5, c = i & 31;
        float s32, c32;
        sincospif((float)((r * c) & 31) / 16.0f, &s32, &c32);
        s32 = -s32;                                  // exp(-2pi i rc/32)
        tabs[i]        = make_float2(c32,  s32);     // F
        tabs[1024 + i] = make_float2(c32, -s32);     // Finv
        float sN, cN;
        sincospif((float)(r * c) / 512.0f, &sN, &cN);
        sN = -sN;                                    // exp(-2pi i rc/1024)
        tabs[2048 + i] = make_float2(cN / 1024.0f, sN / 1024.0f);
        tabs[3072 + i] = make_float2(cN, -sN);
        // T1[m][l] = twiddle[l&31][row(m,l)] (symmetric), WITHOUT the 1/N
        // (1/N is folded into kf_cd).
        int m = i >> 6, l = i & 63;
        int row = (m & 3) + 8 * (m >> 2) + 4 * (l >> 5);
        int prod = (l & 31) * row;
        float st, ct;
        sincospif((float)prod / 512.0f, &st, &ct);
        T1[i] = make_float2(ct, -st);
    }
    if (gid < 1536) {
        // Ftab: 3 comps x 2 ktiles x 64 lanes x 4 vgprs, packed bf16 pairs.
        // comp 0: re(F)=cos ; 1: im(F)=-sin ; 2: +sin
        int c = gid >> 9;
        int rem = gid & 511;
        int t = rem >> 8;
        int sub = rem & 255;
        int l = sub >> 2;
        int v = sub & 3;
        int k0 = 16 * t + 8 * (l >> 5) + 2 * v;
        int j = l & 31;
        unsigned short sh[2];
        for (int q = 0; q < 2; q++) {
            int k = k0 + q;
            float sa, ca;
            sincospif((float)((k * j) & 31) / 16.0f, &sa, &ca);
            float base = (c == 0) ? ca : ((c == 1) ? -sa : sa);
            sh[q] = f2bf(base);
        }
        ((unsigned*)Ftab)[((c * 2 + t) * 64 + l) * 4 + v] =
            (unsigned)sh[0] | ((unsigned)sh[1] << 16);
    }
}

// Filter spectrum kfT[h][k1][k2] = FFT_1024(k[h])[32*k2+k1], written permuted
// AND scaled by 1/1024 (the four-step's 1/N, moved out of the twiddle):
// kf_cd[h][m][l] = kfT[h][l&31][row(m,l)] / 1024
__global__ __launch_bounds__(256) void kf_kernel(const float* __restrict__ kin,
                                                 const float2* __restrict__ tabs,
                                                 float2* __restrict__ kf_cd) {
    __shared__ float  sx[1024];
    __shared__ float2 sA[1024];
    const int h = blockIdx.x, t = threadIdx.x;
    for (int i = t; i < 1024; i += 256) sx[i] = kin[h * 1024 + i];
    __syncthreads();
    const int r = t >> 3, c0 = (t & 7) << 2;

    float2 acc[4];
    for (int j = 0; j < 4; j++) acc[j] = make_float2(0.f, 0.f);
    #pragma unroll 8
    for (int n1 = 0; n1 < 32; n1++) {
        float2 f = tabs[r * 32 + n1];
        for (int j = 0; j < 4; j++) {
            float xv = sx[n1 * 32 + c0 + j];
            acc[j].x += f.x * xv;
            acc[j].y += f.y * xv;
        }
    }
    for (int j = 0; j < 4; j++) {
        float2 w = tabs[3072 + r * 32 + c0 + j];   // conj -> exp(-2pi i rc/N)
        sA[r * 32 + c0 + j] = make_float2(acc[j].x * w.x + acc[j].y * w.y,
                                          acc[j].y * w.x - acc[j].x * w.y);
    }
    __syncthreads();
    for (int j = 0; j < 4; j++) acc[j] = make_float2(0.f, 0.f);
    #pragma unroll 8
    for (int n2 = 0; n2 < 32; n2++) {
        float2 a = sA[r * 32 + n2];
        for (int j = 0; j < 4; j++) {
            float2 f = tabs[n2 * 32 + c0 + j];
            acc[j].x += a.x * f.x - a.y * f.y;
            acc[j].y += a.x * f.y + a.y * f.x;
        }
    }
    for (int j = 0; j < 4; j++) {
        int k2 = c0 + j;
        int m = (k2 & 3) | ((k2 >> 3) << 2);
        int hl = (k2 >> 2) & 1;
        kf_cd[h * 1024 + m * 64 + hl * 32 + r] =
            make_float2(acc[j].x * (1.0f / 1024.0f), acc[j].y * (1.0f / 1024.0f));
    }
}

// C/D accumulator -> bf16 A/B fragment via v_permlane32_swap_b32:
// swap(a,b): a.hi <-> b.lo, so afterwards a = [a.lo;b.lo], b = [a.hi;b.hi]
// -- exactly the two fragment words (replaces 4 shfl_xor + 4 cndmask each).
static __device__ __forceinline__ void convertP(const f32x16& acc, FragH& out) {
    #pragma unroll
    for (int t = 0; t < 2; t++) {
        unsigned a0 = packbf(acc[8 * t + 0], acc[8 * t + 1]);
        unsigned a1 = packbf(acc[8 * t + 2], acc[8 * t + 3]);
        unsigned b0 = packbf(acc[8 * t + 4], acc[8 * t + 5]);
        unsigned b1 = packbf(acc[8 * t + 6], acc[8 * t + 7]);
        asm("v_permlane32_swap_b32 %0, %1" : "+v"(a0), "+v"(b0));
        asm("v_permlane32_swap_b32 %0, %1" : "+v"(a1), "+v"(b1));
        out.f[t].u[0] = a0;
        out.f[t].u[1] = a1;
        out.f[t].u[2] = b0;
        out.f[t].u[3] = b1;
    }
}

// (256,3): cap regs at ~170 (3 waves/SIMD) -- R5's free allocator landed at
// ~2 waves/SIMD (occupancy 26%); R4's (256,4)=64-reg cap spilled. Tables now
// in LDS so ~130-150 regs suffice.
__global__ __launch_bounds__(256, 3) void conv_mfma(const float* __restrict__ u,
                                                    const float2* __restrict__ T1,
                                                    const uint4* __restrict__ Ftab,
                                                    const float2* __restrict__ KF,
                                                    float* __restrict__ out) {
    __shared__ float2 sT1[1024];    // 8 KB: twiddle, C/D order
    __shared__ float2 sKF[1024];    // 8 KB: this block's h filter spectrum

    const int tid = threadIdx.x;
    const int lane = tid & 63;
    const int wave = tid >> 6;
    const int w = blockIdx.x * 4 + wave;     // 0..8191, 2 tiles each
    const int h = blockIdx.x >> 4;           // == w>>6 for all 4 waves
    const int col = lane & 31;
    const int hl = lane >> 5;

    for (int i = tid; i < 1024; i += 256) {
        sT1[i] = T1[i];
        sKF[i] = KF[h * 1024 + i];
    }
    __syncthreads();

    // Fixed F fragment tables (bf16), register-resident.
    // F[0]=re=cos, F[1]=im=-sin, F[2]=+sin
    U F[3][2];
    #pragma unroll
    for (int c = 0; c < 3; c++)
        #pragma unroll
        for (int t = 0; t < 2; t++) {
            uint4 raw = Ftab[(c * 2 + t) * 64 + lane];
            F[c][t].u[0] = raw.x; F[c][t].u[1] = raw.y;
            F[c][t].u[2] = raw.z; F[c][t].u[3] = raw.w;
        }

    const f32x16 Z16 = {0,0,0,0,0,0,0,0,0,0,0,0,0,0,0,0};

    // Prefetch BOTH tiles' inputs up front (HBM latency hides under tile 0).
    U A[2][2];
    #pragma unroll
    for (int i = 0; i < 2; i++) {
        const int b = (w * 2 + i) & 127;
        const float* up = u + ((size_t)(b * 128 + h) << 10);
        #pragma unroll
        for (int t = 0; t < 2; t++) {
            float xv[8];
            #pragma unroll
            for (int e = 0; e < 8; e++)
                xv[e] = up[(16 * t + 8 * hl + e) * 32 + col];
            #pragma unroll
            for (int v = 0; v < 4; v++)
                A[i][t].u[v] = packbf(xv[2 * v], xv[2 * v + 1]);
        }
    }

    #pragma unroll
    for (int i = 0; i < 2; i++) {
        const int b = (w * 2 + i) & 127;

        // ---- Stage 1: Y^T = X^T @ F
        f32x16 aR = Z16, aI = Z16;
        #pragma unroll
        for (int t = 0; t < 2; t++) {
            aR = MFMA(A[i][t], F[0][t], aR);
            aI = MFMA(A[i][t], F[1][t], aI);
        }
        #pragma unroll
        for (int m = 0; m < 16; m++) {                 // twiddle (1/N in kf)
            float2 tm = sT1[m * 64 + lane];
            float rr = aR[m] * tm.x - aI[m] * tm.y;
            float ii = aR[m] * tm.y + aI[m] * tm.x;
            aR[m] = rr; aI[m] = ii;
        }
        FragH Yr, Yi;
        convertP(aR, Yr);
        convertP(aI, Yi);

        // ---- Stage 3: Z^T = F @ Y^T  (Zr = re@Yr + sin@Yi ; Zi = re@Yi + im@Yr)
        f32x16 bR = Z16, bI = Z16;
        #pragma unroll
        for (int t = 0; t < 2; t++) {
            bR = MFMA(F[0][t], Yr.f[t], bR); bR = MFMA(F[2][t], Yi.f[t], bR);
            bI = MFMA(F[0][t], Yi.f[t], bI); bI = MFMA(F[1][t], Yr.f[t], bI);
        }
        #pragma unroll
        for (int m = 0; m < 16; m++) {                 // filter (has 1/N)
            float2 kv = sKF[m * 64 + lane];
            float rr = bR[m] * kv.x - bI[m] * kv.y;
            float ii = bR[m] * kv.y + bI[m] * kv.x;
            bR[m] = rr; bI[m] = ii;
        }
        FragH Zr, Zi;
        convertP(bR, Zr);
        convertP(bI, Zi);

        // ---- Stage 5: W = Z @ Finv  (Wr = Zr@re + Zi@im ; Wi = Zr@sin + Zi@re)
        aR = Z16; aI = Z16;
        #pragma unroll
        for (int t = 0; t < 2; t++) {
            aR = MFMA(Zr.f[t], F[0][t], aR); aR = MFMA(Zi.f[t], F[1][t], aR);
            aI = MFMA(Zr.f[t], F[2][t], aI); aI = MFMA(Zi.f[t], F[0][t], aI);
        }
        #pragma unroll
        for (int m = 0; m < 16; m++) {                 // conj twiddle (no scale)
            float2 tm = sT1[m * 64 + lane];
            float rr = aR[m] * tm.x + aI[m] * tm.y;
            float ii = aI[m] * tm.x - aR[m] * tm.y;
            aR[m] = rr; aI[m] = ii;
        }
        FragH Wr, Wi;
        convertP(aR, Wr);
        convertP(aI, Wi);

        // ---- Stage 7: y = Re(Finv @ W) = re@Wr + im@Wi
        f32x16 yR = Z16;
        #pragma unroll
        for (int t = 0; t < 2; t++) {
            yR = MFMA(F[0][t], Wr.f[t], yR);
            yR = MFMA(F[1][t], Wi.f[t], yR);
        }
        float* op = out + ((size_t)(b * 128 + h) << 10);
        #pragma unroll
        for (int m = 0; m < 16; m++)
            op[((m & 3) + 8 * (m >> 2) + 4 * hl) * 32 + col] = yR[m];
    }
}

extern "C" void kernel_launch(void* const* d_in, const int* in_sizes, int n_in,
                              void* d_out, int out_size, void* d_ws, size_t ws_size,
                              hipStream_t stream) {
    const float* u = (const float*)d_in[0];   // (B=128, H=128, N=1024)
    const float* k = (const float*)d_in[1];   // (H=128, N=1024)
    float* out = (float*)d_out;               // (B, H, N) float32

    float2* tabs  = (float2*)d_ws;
    float2* T1    = (float2*)((char*)d_ws + 32768);
    uint4*  Ftab  = (uint4*)((char*)d_ws + 49152);
    float2* kf_cd = (float2*)((char*)d_ws + 65536);

    fft_tables<<<16, 256, 0, stream>>>(tabs, T1, Ftab);
    kf_kernel<<<128, 256, 0, stream>>>(k, tabs, kf_cd);
    conv_mfma<<<2048, 256, 0, stream>>>(u, T1, Ftab, kf_cd, out);
}

// Round 7
// 46.336 us; speedup vs baseline: 1.3072x; 1.3072x over previous
//
#include <hip/hip_runtime.h>
#include <hip/hip_bf16.h>
#include <math.h>

typedef __attribute__((ext_vector_type(8))) short short8;
typedef __attribute__((ext_vector_type(16))) float f32x16;

union U {
    unsigned u[4];
    short8 s;
};

struct FragH {         // one component (re or im) bf16 operand, 2 k-tiles
    U f[2];
};

static __device__ __forceinline__ unsigned short f2bf(float x) {
    __bf16 b = (__bf16)x;                       // RNE, native v_cvt on gfx950
    return __builtin_bit_cast(unsigned short, b);
}
static __device__ __forceinline__ unsigned packbf(float a, float b) {
    return (unsigned)f2bf(a) | ((unsigned)f2bf(b) << 16);
}

#define MFMA(A, B, C) __builtin_amdgcn_mfma_f32_32x32x16_bf16((A).s, (B).s, (C), 0, 0, 0)

// ---------------------------------------------------------------------------
// Workspace layout (bytes):
//   0      : tabs  float2[4096]  (F, Finv, -, conj-twiddle -- for kf_kernel)
//   32768  : T1    float2[1024]  (pure twiddle exp(-2pi i rc/N), C/D order; NO 1/N)
//   49152  : Ftab  uint4 [384]   (bf16 fragment tables: re, im, +sin)
//   65536  : kf_cd float2[128*1024] (filter spectrum / 1024, C/D order)
// ---------------------------------------------------------------------------

__global__ __launch_bounds__(256) void fft_tables(float2* tabs, float2* T1, uint4* Ftab) {
    int gid = blockIdx.x * 256 + threadIdx.x;       // grid 16*256 = 4096
    if (gid < 1024) {
        int i = gid;
        int r = i >> 5, c = i & 31;
        float s32, c32;
        sincospif((float)((r * c) & 31) / 16.0f, &s32, &c32);
        s32 = -s32;                                  // exp(-2pi i rc/32)
        tabs[i]        = make_float2(c32,  s32);     // F
        tabs[1024 + i] = make_float2(c32, -s32);     // Finv
        float sN, cN;
        sincospif((float)(r * c) / 512.0f, &sN, &cN);
        sN = -sN;                                    // exp(-2pi i rc/1024)
        tabs[2048 + i] = make_float2(cN / 1024.0f, sN / 1024.0f);
        tabs[3072 + i] = make_float2(cN, -sN);
        // T1[m][l] = twiddle[l&31][row(m,l)] (symmetric), WITHOUT the 1/N
        // (1/N is folded into kf_cd).
        int m = i >> 6, l = i & 63;
        int row = (m & 3) + 8 * (m >> 2) + 4 * (l >> 5);
        int prod = (l & 31) * row;
        float st, ct;
        sincospif((float)prod / 512.0f, &st, &ct);
        T1[i] = make_float2(ct, -st);
    }
    if (gid < 1536) {
        // Ftab: 3 comps x 2 ktiles x 64 lanes x 4 vgprs, packed bf16 pairs.
        // comp 0: re(F)=cos ; 1: im(F)=-sin ; 2: +sin
        int c = gid >> 9;
        int rem = gid & 511;
        int t = rem >> 8;
        int sub = rem & 255;
        int l = sub >> 2;
        int v = sub & 3;
        int k0 = 16 * t + 8 * (l >> 5) + 2 * v;
        int j = l & 31;
        unsigned short sh[2];
        for (int q = 0; q < 2; q++) {
            int k = k0 + q;
            float sa, ca;
            sincospif((float)((k * j) & 31) / 16.0f, &sa, &ca);
            float base = (c == 0) ? ca : ((c == 1) ? -sa : sa);
            sh[q] = f2bf(base);
        }
        ((unsigned*)Ftab)[((c * 2 + t) * 64 + l) * 4 + v] =
            (unsigned)sh[0] | ((unsigned)sh[1] << 16);
    }
}

// Filter spectrum kfT[h][k1][k2] = FFT_1024(k[h])[32*k2+k1], written permuted
// AND scaled by 1/1024 (the four-step's 1/N, moved out of the twiddle):
// kf_cd[h][m][l] = kfT[h][l&31][row(m,l)] / 1024
__global__ __launch_bounds__(256) void kf_kernel(const float* __restrict__ kin,
                                                 const float2* __restrict__ tabs,
                                                 float2* __restrict__ kf_cd) {
    __shared__ float  sx[1024];
    __shared__ float2 sA[1024];
    const int h = blockIdx.x, t = threadIdx.x;
    for (int i = t; i < 1024; i += 256) sx[i] = kin[h * 1024 + i];
    __syncthreads();
    const int r = t >> 3, c0 = (t & 7) << 2;

    float2 acc[4];
    for (int j = 0; j < 4; j++) acc[j] = make_float2(0.f, 0.f);
    #pragma unroll 8
    for (int n1 = 0; n1 < 32; n1++) {
        float2 f = tabs[r * 32 + n1];
        for (int j = 0; j < 4; j++) {
            float xv = sx[n1 * 32 + c0 + j];
            acc[j].x += f.x * xv;
            acc[j].y += f.y * xv;
        }
    }
    for (int j = 0; j < 4; j++) {
        float2 w = tabs[3072 + r * 32 + c0 + j];   // conj -> exp(-2pi i rc/N)
        sA[r * 32 + c0 + j] = make_float2(acc[j].x * w.x + acc[j].y * w.y,
                                          acc[j].y * w.x - acc[j].x * w.y);
    }
    __syncthreads();
    for (int j = 0; j < 4; j++) acc[j] = make_float2(0.f, 0.f);
    #pragma unroll 8
    for (int n2 = 0; n2 < 32; n2++) {
        float2 a = sA[r * 32 + n2];
        for (int j = 0; j < 4; j++) {
            float2 f = tabs[n2 * 32 + c0 + j];
            acc[j].x += a.x * f.x - a.y * f.y;
            acc[j].y += a.x * f.y + a.y * f.x;
        }
    }
    for (int j = 0; j < 4; j++) {
        int k2 = c0 + j;
        int m = (k2 & 3) | ((k2 >> 3) << 2);
        int hl = (k2 >> 2) & 1;
        kf_cd[h * 1024 + m * 64 + hl * 32 + r] =
            make_float2(acc[j].x * (1.0f / 1024.0f), acc[j].y * (1.0f / 1024.0f));
    }
}

// C/D accumulator -> bf16 A/B fragment via v_permlane32_swap_b32:
// swap(a,b): a.hi <-> b.lo => a = [a.lo;b.lo], b = [a.hi;b.hi]
static __device__ __forceinline__ void convertP(const f32x16& acc, FragH& out) {
    #pragma unroll
    for (int t = 0; t < 2; t++) {
        unsigned a0 = packbf(acc[8 * t + 0], acc[8 * t + 1]);
        unsigned a1 = packbf(acc[8 * t + 2], acc[8 * t + 3]);
        unsigned b0 = packbf(acc[8 * t + 4], acc[8 * t + 5]);
        unsigned b1 = packbf(acc[8 * t + 6], acc[8 * t + 7]);
        asm("v_permlane32_swap_b32 %0, %1" : "+v"(a0), "+v"(b0));
        asm("v_permlane32_swap_b32 %0, %1" : "+v"(a1), "+v"(b1));
        out.f[t].u[0] = a0;
        out.f[t].u[1] = a1;
        out.f[t].u[2] = b0;
        out.f[t].u[3] = b1;
    }
}

// ONE tile per wave (grid 4096 x 4 waves = 16384 tiles): peak live set
// ~130-140 unified regs -> fits the 170-reg budget of 3 waves/SIMD without
// spilling (R6's 2-tile form at (256,3) spilled: WRITE 65->125 MB).
__global__ __launch_bounds__(256, 3) void conv_mfma(const float* __restrict__ u,
                                                    const float2* __restrict__ T1,
                                                    const uint4* __restrict__ Ftab,
                                                    const float2* __restrict__ KF,
                                                    float* __restrict__ out) {
    __shared__ float2 sT1[1024];    // 8 KB: twiddle, C/D order
    __shared__ float2 sKF[1024];    // 8 KB: this block's h filter spectrum

    const int tid = threadIdx.x;
    const int lane = tid & 63;
    const int wave = tid >> 6;
    const int w = blockIdx.x * 4 + wave;     // tile id 0..16383
    const int h = blockIdx.x >> 5;           // == w>>7 for all 4 waves
    const int b = w & 127;
    const int col = lane & 31;
    const int hl = lane >> 5;

    for (int i = tid; i < 1024; i += 256) {
        sT1[i] = T1[i];
        sKF[i] = KF[h * 1024 + i];
    }
    __syncthreads();

    // Fixed F fragment tables (bf16), register-resident.
    // F[0]=re=cos, F[1]=im=-sin, F[2]=+sin
    U F[3][2];
    #pragma unroll
    for (int c = 0; c < 3; c++)
        #pragma unroll
        for (int t = 0; t < 2; t++) {
            uint4 raw = Ftab[(c * 2 + t) * 64 + lane];
            F[c][t].u[0] = raw.x; F[c][t].u[1] = raw.y;
            F[c][t].u[2] = raw.z; F[c][t].u[3] = raw.w;
        }

    const f32x16 Z16 = {0,0,0,0,0,0,0,0,0,0,0,0,0,0,0,0};

    // ---- Input: A = X^T direct from global, single bf16.
    const float* up = u + ((size_t)(b * 128 + h) << 10);
    U A[2];
    #pragma unroll
    for (int t = 0; t < 2; t++) {
        float xv[8];
        #pragma unroll
        for (int e = 0; e < 8; e++)
            xv[e] = up[(16 * t + 8 * hl + e) * 32 + col];
        #pragma unroll
        for (int v = 0; v < 4; v++)
            A[t].u[v] = packbf(xv[2 * v], xv[2 * v + 1]);
    }

    // ---- Stage 1: Y^T = X^T @ F
    f32x16 aR = Z16, aI = Z16;
    #pragma unroll
    for (int t = 0; t < 2; t++) {
        aR = MFMA(A[t], F[0][t], aR);
        aI = MFMA(A[t], F[1][t], aI);
    }
    #pragma unroll
    for (int m = 0; m < 16; m++) {                 // twiddle (1/N in kf)
        float2 tm = sT1[m * 64 + lane];
        float rr = aR[m] * tm.x - aI[m] * tm.y;
        float ii = aR[m] * tm.y + aI[m] * tm.x;
        aR[m] = rr; aI[m] = ii;
    }
    FragH Yr, Yi;
    convertP(aR, Yr);
    convertP(aI, Yi);

    // ---- Stage 3: Z^T = F @ Y^T  (Zr = re@Yr + sin@Yi ; Zi = re@Yi + im@Yr)
    f32x16 bR = Z16, bI = Z16;
    #pragma unroll
    for (int t = 0; t < 2; t++) {
        bR = MFMA(F[0][t], Yr.f[t], bR); bR = MFMA(F[2][t], Yi.f[t], bR);
        bI = MFMA(F[0][t], Yi.f[t], bI); bI = MFMA(F[1][t], Yr.f[t], bI);
    }
    #pragma unroll
    for (int m = 0; m < 16; m++) {                 // filter (has 1/N)
        float2 kv = sKF[m * 64 + lane];
        float rr = bR[m] * kv.x - bI[m] * kv.y;
        float ii = bR[m] * kv.y + bI[m] * kv.x;
        bR[m] = rr; bI[m] = ii;
    }
    FragH Zr, Zi;
    convertP(bR, Zr);
    convertP(bI, Zi);

    // ---- Stage 5: W = Z @ Finv  (Wr = Zr@re + Zi@im ; Wi = Zr@sin + Zi@re)
    aR = Z16; aI = Z16;
    #pragma unroll
    for (int t = 0; t < 2; t++) {
        aR = MFMA(Zr.f[t], F[0][t], aR); aR = MFMA(Zi.f[t], F[1][t], aR);
        aI = MFMA(Zr.f[t], F[2][t], aI); aI = MFMA(Zi.f[t], F[0][t], aI);
    }
    #pragma unroll
    for (int m = 0; m < 16; m++) {                 // conj twiddle (no scale)
        float2 tm = sT1[m * 64 + lane];
        float rr = aR[m] * tm.x + aI[m] * tm.y;
        float ii = aI[m] * tm.x - aR[m] * tm.y;
        aR[m] = rr; aI[m] = ii;
    }
    FragH Wr, Wi;
    convertP(aR, Wr);
    convertP(aI, Wi);

    // ---- Stage 7: y = Re(Finv @ W) = re@Wr + im@Wi
    f32x16 yR = Z16;
    #pragma unroll
    for (int t = 0; t < 2; t++) {
        yR = MFMA(F[0][t], Wr.f[t], yR);
        yR = MFMA(F[1][t], Wi.f[t], yR);
    }
    float* op = out + ((size_t)(b * 128 + h) << 10);
    #pragma unroll
    for (int m = 0; m < 16; m++)
        op[((m & 3) + 8 * (m >> 2) + 4 * hl) * 32 + col] = yR[m];
}

extern "C" void kernel_launch(void* const* d_in, const int* in_sizes, int n_in,
                              void* d_out, int out_size, void* d_ws, size_t ws_size,
                              hipStream_t stream) {
    const float* u = (const float*)d_in[0];   // (B=128, H=128, N=1024)
    const float* k = (const float*)d_in[1];   // (H=128, N=1024)
    float* out = (float*)d_out;               // (B, H, N) float32

    float2* tabs  = (float2*)d_ws;
    float2* T1    = (float2*)((char*)d_ws + 32768);
    uint4*  Ftab  = (uint4*)((char*)d_ws + 49152);
    float2* kf_cd = (float2*)((char*)d_ws + 65536);

    fft_tables<<<16, 256, 0, stream>>>(tabs, T1, Ftab);
    kf_kernel<<<128, 256, 0, stream>>>(k, tabs, kf_cd);
    conv_mfma<<<4096, 256, 0, stream>>>(u, T1, Ftab, kf_cd, out);
}

// Round 8
// 43.239 us; speedup vs baseline: 1.4008x; 1.0716x over previous
//
#include <hip/hip_runtime.h>
#include <hip/hip_bf16.h>
#include <math.h>

typedef __attribute__((ext_vector_type(8))) short short8;
typedef __attribute__((ext_vector_type(16))) float f32x16;

union U {
    unsigned u[4];
    short8 s;
};

struct FragH {         // one component (re or im) bf16 operand, 2 k-tiles
    U f[2];
};

static __device__ __forceinline__ unsigned short f2bf(float x) {
    __bf16 b = (__bf16)x;                       // RNE, native v_cvt on gfx950
    return __builtin_bit_cast(unsigned short, b);
}
static __device__ __forceinline__ unsigned packbf(float a, float b) {
    return (unsigned)f2bf(a) | ((unsigned)f2bf(b) << 16);
}

#define MFMA(A, B, C) __builtin_amdgcn_mfma_f32_32x32x16_bf16((A).s, (B).s, (C), 0, 0, 0)

// ---------------------------------------------------------------------------
// Workspace layout (bytes):
//   0      : tabs  float2[4096]  (F, Finv, -, conj-twiddle -- for kf_kernel)
//   32768  : T1    float2[1024]  (pure twiddle exp(-2pi i rc/N), C/D order; NO 1/N)
//   49152  : Ftab  uint4 [384]   (bf16 fragment tables: cos, -sin, +sin)
//   65536  : kf_cd float2[128*1024] (filter spectrum / 1024, C/D order)
// ---------------------------------------------------------------------------

__global__ __launch_bounds__(256) void fft_tables(float2* tabs, float2* T1, uint4* Ftab) {
    int gid = blockIdx.x * 256 + threadIdx.x;       // grid 16*256 = 4096
    if (gid < 1024) {
        int i = gid;
        int r = i >> 5, c = i & 31;
        float s32, c32;
        sincospif((float)((r * c) & 31) / 16.0f, &s32, &c32);
        s32 = -s32;                                  // exp(-2pi i rc/32)
        tabs[i]        = make_float2(c32,  s32);     // F
        tabs[1024 + i] = make_float2(c32, -s32);     // Finv
        float sN, cN;
        sincospif((float)(r * c) / 512.0f, &sN, &cN);
        sN = -sN;                                    // exp(-2pi i rc/1024)
        tabs[2048 + i] = make_float2(cN / 1024.0f, sN / 1024.0f);
        tabs[3072 + i] = make_float2(cN, -sN);
        // T1[m][l] = twiddle[l&31][row(m,l)] (symmetric), WITHOUT the 1/N
        // (1/N is folded into kf_cd).
        int m = i >> 6, l = i & 63;
        int row = (m & 3) + 8 * (m >> 2) + 4 * (l >> 5);
        int prod = (l & 31) * row;
        float st, ct;
        sincospif((float)prod / 512.0f, &st, &ct);
        T1[i] = make_float2(ct, -st);
    }
    if (gid < 1536) {
        // Ftab: 3 comps x 2 ktiles x 64 lanes x 4 vgprs, packed bf16 pairs.
        // comp 0: cos ; 1: -sin (=im F) ; 2: +sin (=im Finv)
        int c = gid >> 9;
        int rem = gid & 511;
        int t = rem >> 8;
        int sub = rem & 255;
        int l = sub >> 2;
        int v = sub & 3;
        int k0 = 16 * t + 8 * (l >> 5) + 2 * v;
        int j = l & 31;
        unsigned short sh[2];
        for (int q = 0; q < 2; q++) {
            int k = k0 + q;
            float sa, ca;
            sincospif((float)((k * j) & 31) / 16.0f, &sa, &ca);
            float base = (c == 0) ? ca : ((c == 1) ? -sa : sa);
            sh[q] = f2bf(base);
        }
        ((unsigned*)Ftab)[((c * 2 + t) * 64 + l) * 4 + v] =
            (unsigned)sh[0] | ((unsigned)sh[1] << 16);
    }
}

// Filter spectrum kfT[h][k1][k2] = FFT_1024(k[h])[32*k2+k1], written permuted
// AND scaled by 1/1024: kf_cd[h][m][l] = kfT[h][l&31][row(m,l)] / 1024
__global__ __launch_bounds__(256) void kf_kernel(const float* __restrict__ kin,
                                                 const float2* __restrict__ tabs,
                                                 float2* __restrict__ kf_cd) {
    __shared__ float  sx[1024];
    __shared__ float2 sA[1024];
    const int h = blockIdx.x, t = threadIdx.x;
    for (int i = t; i < 1024; i += 256) sx[i] = kin[h * 1024 + i];
    __syncthreads();
    const int r = t >> 3, c0 = (t & 7) << 2;

    float2 acc[4];
    for (int j = 0; j < 4; j++) acc[j] = make_float2(0.f, 0.f);
    #pragma unroll 8
    for (int n1 = 0; n1 < 32; n1++) {
        float2 f = tabs[r * 32 + n1];
        for (int j = 0; j < 4; j++) {
            float xv = sx[n1 * 32 + c0 + j];
            acc[j].x += f.x * xv;
            acc[j].y += f.y * xv;
        }
    }
    for (int j = 0; j < 4; j++) {
        float2 w = tabs[3072 + r * 32 + c0 + j];   // conj -> exp(-2pi i rc/N)
        sA[r * 32 + c0 + j] = make_float2(acc[j].x * w.x + acc[j].y * w.y,
                                          acc[j].y * w.x - acc[j].x * w.y);
    }
    __syncthreads();
    for (int j = 0; j < 4; j++) acc[j] = make_float2(0.f, 0.f);
    #pragma unroll 8
    for (int n2 = 0; n2 < 32; n2++) {
        float2 a = sA[r * 32 + n2];
        for (int j = 0; j < 4; j++) {
            float2 f = tabs[n2 * 32 + c0 + j];
            acc[j].x += a.x * f.x - a.y * f.y;
            acc[j].y += a.x * f.y + a.y * f.x;
        }
    }
    for (int j = 0; j < 4; j++) {
        int k2 = c0 + j;
        int m = (k2 & 3) | ((k2 >> 3) << 2);
        int hl = (k2 >> 2) & 1;
        kf_cd[h * 1024 + m * 64 + hl * 32 + r] =
            make_float2(acc[j].x * (1.0f / 1024.0f), acc[j].y * (1.0f / 1024.0f));
    }
}

// C/D accumulator -> bf16 A/B fragment via v_permlane32_swap_b32:
// swap(a,b): a.hi <-> b.lo => a = [a.lo;b.lo], b = [a.hi;b.hi]
static __device__ __forceinline__ void convertP(const f32x16& acc, FragH& out) {
    #pragma unroll
    for (int t = 0; t < 2; t++) {
        unsigned a0 = packbf(acc[8 * t + 0], acc[8 * t + 1]);
        unsigned a1 = packbf(acc[8 * t + 2], acc[8 * t + 3]);
        unsigned b0 = packbf(acc[8 * t + 4], acc[8 * t + 5]);
        unsigned b1 = packbf(acc[8 * t + 6], acc[8 * t + 7]);
        asm("v_permlane32_swap_b32 %0, %1" : "+v"(a0), "+v"(b0));
        asm("v_permlane32_swap_b32 %0, %1" : "+v"(a1), "+v"(b1));
        out.f[t].u[0] = a0;
        out.f[t].u[1] = a1;
        out.f[t].u[2] = b0;
        out.f[t].u[3] = b1;
    }
}

// Real-input packing: z = u[b0] + i*u[b0+1]; conv is linear and k is real, so
// ifft(fft(z)*kf) = y[b0] + i*y[b0+1]. One complex four-step pipeline produces
// TWO output tiles: Re -> b0, Im -> b0+1. Halves twiddle/convert VALU and
// cuts MFMA 48->32 per tile-pair.
__global__ __launch_bounds__(256, 3) void conv_mfma(const float* __restrict__ u,
                                                    const float2* __restrict__ T1,
                                                    const uint4* __restrict__ Ftab,
                                                    const float2* __restrict__ KF,
                                                    float* __restrict__ out) {
    __shared__ float2 sT1[1024];    // 8 KB: twiddle, C/D order
    __shared__ float2 sKF[1024];    // 8 KB: this block's h filter spectrum

    const int tid = threadIdx.x;
    const int lane = tid & 63;
    const int wave = tid >> 6;
    const int p = blockIdx.x * 4 + wave;     // pair id 0..8191
    const int h = blockIdx.x >> 4;           // == p>>6 for all 4 waves
    const int b0 = (p & 63) * 2;             // b0, b0+1 handled together
    const int col = lane & 31;
    const int hl = lane >> 5;

    for (int i = tid; i < 1024; i += 256) {
        sT1[i] = T1[i];
        sKF[i] = KF[h * 1024 + i];
    }
    __syncthreads();

    // F fragment tables (bf16): F[0]=cos, F[1]=-sin, F[2]=+sin
    U F[3][2];
    #pragma unroll
    for (int c = 0; c < 3; c++)
        #pragma unroll
        for (int t = 0; t < 2; t++) {
            uint4 raw = Ftab[(c * 2 + t) * 64 + lane];
            F[c][t].u[0] = raw.x; F[c][t].u[1] = raw.y;
            F[c][t].u[2] = raw.z; F[c][t].u[3] = raw.w;
        }

    const f32x16 Z16 = {0,0,0,0,0,0,0,0,0,0,0,0,0,0,0,0};

    // ---- Input: Xr = u[b0] tile, Xi = u[b0+1] tile (transposed read).
    const float* up0 = u + ((size_t)(b0 * 128 + h) << 10);
    const float* up1 = up0 + (size_t)128 * 1024;
    U Xr[2], Xi[2];
    #pragma unroll
    for (int t = 0; t < 2; t++) {
        float xr[8], xi[8];
        #pragma unroll
        for (int e = 0; e < 8; e++) {
            int off = (16 * t + 8 * hl + e) * 32 + col;
            xr[e] = up0[off];
            xi[e] = up1[off];
        }
        #pragma unroll
        for (int v = 0; v < 4; v++) {
            Xr[t].u[v] = packbf(xr[2 * v], xr[2 * v + 1]);
            Xi[t].u[v] = packbf(xi[2 * v], xi[2 * v + 1]);
        }
    }

    // ---- Stage 1: Y^T = Z^T @ F, Z = Xr + i*Xi, F = C + iS (S = -sin)
    // Yr = Xr@C + Xi@(+sin) ; Yi = Xr@S + Xi@C
    f32x16 aR = Z16, aI = Z16;
    #pragma unroll
    for (int t = 0; t < 2; t++) {
        aR = MFMA(Xr[t], F[0][t], aR); aR = MFMA(Xi[t], F[2][t], aR);
        aI = MFMA(Xr[t], F[1][t], aI); aI = MFMA(Xi[t], F[0][t], aI);
    }
    #pragma unroll
    for (int m = 0; m < 16; m++) {                 // twiddle (1/N in kf)
        float2 tm = sT1[m * 64 + lane];
        float rr = aR[m] * tm.x - aI[m] * tm.y;
        float ii = aR[m] * tm.y + aI[m] * tm.x;
        aR[m] = rr; aI[m] = ii;
    }
    FragH Yr, Yi;
    convertP(aR, Yr);
    convertP(aI, Yi);

    // ---- Stage 3: Z^T = F @ Y^T  (Zr = C@Yr + sin@Yi ; Zi = C@Yi + S@Yr)
    f32x16 bR = Z16, bI = Z16;
    #pragma unroll
    for (int t = 0; t < 2; t++) {
        bR = MFMA(F[0][t], Yr.f[t], bR); bR = MFMA(F[2][t], Yi.f[t], bR);
        bI = MFMA(F[0][t], Yi.f[t], bI); bI = MFMA(F[1][t], Yr.f[t], bI);
    }
    #pragma unroll
    for (int m = 0; m < 16; m++) {                 // filter (has 1/N)
        float2 kv = sKF[m * 64 + lane];
        float rr = bR[m] * kv.x - bI[m] * kv.y;
        float ii = bR[m] * kv.y + bI[m] * kv.x;
        bR[m] = rr; bI[m] = ii;
    }
    FragH Zr, Zi;
    convertP(bR, Zr);
    convertP(bI, Zi);

    // ---- Stage 5: W = Z @ Finv  (Wr = Zr@C + Zi@S ; Wi = Zr@sin + Zi@C)
    aR = Z16; aI = Z16;
    #pragma unroll
    for (int t = 0; t < 2; t++) {
        aR = MFMA(Zr.f[t], F[0][t], aR); aR = MFMA(Zi.f[t], F[1][t], aR);
        aI = MFMA(Zr.f[t], F[2][t], aI); aI = MFMA(Zi.f[t], F[0][t], aI);
    }
    #pragma unroll
    for (int m = 0; m < 16; m++) {                 // conj twiddle (no scale)
        float2 tm = sT1[m * 64 + lane];
        float rr = aR[m] * tm.x + aI[m] * tm.y;
        float ii = aI[m] * tm.x - aR[m] * tm.y;
        aR[m] = rr; aI[m] = ii;
    }
    FragH Wr, Wi;
    convertP(aR, Wr);
    convertP(aI, Wi);

    // ---- Stage 7: y = Finv @ W  (yR = C@Wr + S@Wi ; yI = C@Wi + sin@Wr)
    f32x16 yR = Z16, yI = Z16;
    #pragma unroll
    for (int t = 0; t < 2; t++) {
        yR = MFMA(F[0][t], Wr.f[t], yR); yR = MFMA(F[1][t], Wi.f[t], yR);
        yI = MFMA(F[0][t], Wi.f[t], yI); yI = MFMA(F[2][t], Wr.f[t], yI);
    }
    float* op0 = out + ((size_t)(b0 * 128 + h) << 10);
    float* op1 = op0 + (size_t)128 * 1024;
    #pragma unroll
    for (int m = 0; m < 16; m++) {
        int off = ((m & 3) + 8 * (m >> 2) + 4 * hl) * 32 + col;
        op0[off] = yR[m];
        op1[off] = yI[m];
    }
}

extern "C" void kernel_launch(void* const* d_in, const int* in_sizes, int n_in,
                              void* d_out, int out_size, void* d_ws, size_t ws_size,
                              hipStream_t stream) {
    const float* u = (const float*)d_in[0];   // (B=128, H=128, N=1024)
    const float* k = (const float*)d_in[1];   // (H=128, N=1024)
    float* out = (float*)d_out;               // (B, H, N) float32

    float2* tabs  = (float2*)d_ws;
    float2* T1    = (float2*)((char*)d_ws + 32768);
    uint4*  Ftab  = (uint4*)((char*)d_ws + 49152);
    float2* kf_cd = (float2*)((char*)d_ws + 65536);

    fft_tables<<<16, 256, 0, stream>>>(tabs, T1, Ftab);
    kf_kernel<<<128, 256, 0, stream>>>(k, tabs, kf_cd);
    conv_mfma<<<2048, 256, 0, stream>>>(u, T1, Ftab, kf_cd, out);
}